// Round 1
// baseline (145.209 us; speedup 1.0000x reference)
//
#include <hip/hip_runtime.h>

// Precompute per-face interpolatable vertex scores: fc[f] = (v0, v1, v2, 0)
__global__ void face_attr_kernel(const float* __restrict__ verts,
                                 const int* __restrict__ faces,
                                 float4* __restrict__ fc, int F) {
    int f = blockIdx.x * blockDim.x + threadIdx.x;
    if (f < F) {
        int i0 = faces[f * 3 + 0];
        int i1 = faces[f * 3 + 1];
        int i2 = faces[f * 3 + 2];
        fc[f] = make_float4(verts[i0], verts[i1], verts[i2], 0.0f);
    }
}

// One thread per pixel, handling both K=2 slots.
// pix_to_face: [nPix][2] int32  -> int2
// bary:        [nPix][2][3] f32 -> 3x float2 per pixel (8B-aligned, 24B stride)
// fc:          [F] float4 (L2-resident, 1.76 MB)
// out:         [nPix][2] int32  -> int2
__global__ void seg_kernel(const int2* __restrict__ p2f,
                           const float2* __restrict__ bary,
                           const float4* __restrict__ fc,
                           int2* __restrict__ out, long nPix) {
    long stride = (long)gridDim.x * blockDim.x;
    for (long i = (long)blockIdx.x * blockDim.x + threadIdx.x; i < nPix; i += stride) {
        int2 p = p2f[i];
        float2 b01 = bary[i * 3 + 0];   // k0c0, k0c1
        float2 b23 = bary[i * 3 + 1];   // k0c2, k1c0
        float2 b45 = bary[i * 3 + 2];   // k1c1, k1c2
        int r0 = 0, r1 = 0;
        if (p.x >= 0) {
            float4 f = fc[p.x];
            float v = b01.x * f.x + b01.y * f.y + b23.x * f.z;
            r0 = (int)v;
        }
        if (p.y >= 0) {
            float4 f = fc[p.y];
            float v = b23.y * f.x + b45.x * f.y + b45.y * f.z;
            r1 = (int)v;
        }
        out[i] = make_int2(r0, r1);
    }
}

// Fallback: fused double-gather (used only if ws_size is too small).
__global__ void seg_fused_kernel(const int2* __restrict__ p2f,
                                 const float2* __restrict__ bary,
                                 const float* __restrict__ verts,
                                 const int* __restrict__ faces,
                                 int2* __restrict__ out, long nPix) {
    long stride = (long)gridDim.x * blockDim.x;
    for (long i = (long)blockIdx.x * blockDim.x + threadIdx.x; i < nPix; i += stride) {
        int2 p = p2f[i];
        float2 b01 = bary[i * 3 + 0];
        float2 b23 = bary[i * 3 + 1];
        float2 b45 = bary[i * 3 + 2];
        int r0 = 0, r1 = 0;
        if (p.x >= 0) {
            float f0 = verts[faces[p.x * 3 + 0]];
            float f1 = verts[faces[p.x * 3 + 1]];
            float f2 = verts[faces[p.x * 3 + 2]];
            r0 = (int)(b01.x * f0 + b01.y * f1 + b23.x * f2);
        }
        if (p.y >= 0) {
            float f0 = verts[faces[p.y * 3 + 0]];
            float f1 = verts[faces[p.y * 3 + 1]];
            float f2 = verts[faces[p.y * 3 + 2]];
            r1 = (int)(b23.y * f0 + b45.x * f1 + b45.y * f2);
        }
        out[i] = make_int2(r0, r1);
    }
}

extern "C" void kernel_launch(void* const* d_in, const int* in_sizes, int n_in,
                              void* d_out, int out_size, void* d_ws, size_t ws_size,
                              hipStream_t stream) {
    const float* verts = (const float*)d_in[0];   // [N*V*D] f32, D=1
    const int*   faces = (const int*)d_in[1];     // [F,3] i32
    const int*   p2f   = (const int*)d_in[2];     // [N,H,W,K] i32
    const float* bary  = (const float*)d_in[3];   // [N,H,W,K,3] f32

    int  F    = in_sizes[1] / 3;
    long nPix = (long)in_sizes[2] / 2;            // K = 2
    int* out  = (int*)d_out;

    const int BLK = 256;
    const int GRID = 2048;                        // grid-stride, ~8 blocks/CU

    size_t need = (size_t)F * sizeof(float4);
    if (ws_size >= need) {
        face_attr_kernel<<<(F + BLK - 1) / BLK, BLK, 0, stream>>>(
            verts, faces, (float4*)d_ws, F);
        seg_kernel<<<GRID, BLK, 0, stream>>>(
            (const int2*)p2f, (const float2*)bary, (const float4*)d_ws,
            (int2*)out, nPix);
    } else {
        seg_fused_kernel<<<GRID, BLK, 0, stream>>>(
            (const int2*)p2f, (const float2*)bary, verts, faces,
            (int2*)out, nPix);
    }
}

// Round 3
// 103.761 us; speedup vs baseline: 1.3994x; 1.3994x over previous
//
#include <hip/hip_runtime.h>

typedef int   v4i __attribute__((ext_vector_type(4)));
typedef float v4f __attribute__((ext_vector_type(4)));

// Precompute per-face interpolatable vertex scores: fc[f] = (v0, v1, v2, 0)
__global__ void face_attr_kernel(const float* __restrict__ verts,
                                 const int* __restrict__ faces,
                                 v4f* __restrict__ fc, int F) {
    int f = blockIdx.x * blockDim.x + threadIdx.x;
    if (f < F) {
        int i0 = faces[f * 3 + 0];
        int i1 = faces[f * 3 + 1];
        int i2 = faces[f * 3 + 2];
        v4f v = {verts[i0], verts[i1], verts[i2], 0.0f};
        fc[f] = v;
    }
}

// 4 pixels (8 K-slots) per thread. All loads issued independently for MLP:
//   p2f:  2x v4i   (8 ints,   32 B)
//   bary: 6x v4f   (24 floats, 96 B)
//   fc:   8x v4f clamped gathers (masked after, no branch)
//   out:  2x v4i nontemporal stores
__global__ void __launch_bounds__(256)
seg_kernel(const int* __restrict__ p2f,
           const float* __restrict__ bary,
           const v4f* __restrict__ fc,
           int* __restrict__ out, long nPix) {
    long t = (long)blockIdx.x * blockDim.x + threadIdx.x;
    long base = t * 4;                       // first pixel of this thread

    if (base + 4 <= nPix) {
        const v4i* p4 = (const v4i*)(p2f + base * 2);
        v4i pA = p4[0];                      // px0{k0,k1}, px1{k0,k1}
        v4i pB = p4[1];                      // px2{k0,k1}, px3{k0,k1}

        const v4f* b4 = (const v4f*)(bary + base * 6);
        v4f b0 = b4[0], b1 = b4[1], b2 = b4[2];
        v4f b3 = b4[3], b4v = b4[4], b5 = b4[5];

        // Issue all 8 gathers (clamp negative to 0; mask later).
        v4f f0 = fc[max(pA.x, 0)];
        v4f f1 = fc[max(pA.y, 0)];
        v4f f2 = fc[max(pA.z, 0)];
        v4f f3 = fc[max(pA.w, 0)];
        v4f f4 = fc[max(pB.x, 0)];
        v4f f5 = fc[max(pB.y, 0)];
        v4f f6 = fc[max(pB.z, 0)];
        v4f f7 = fc[max(pB.w, 0)];

        v4i rA, rB;
        rA.x = pA.x < 0 ? 0 : (int)(b0.x * f0.x + b0.y * f0.y + b0.z * f0.z);
        rA.y = pA.y < 0 ? 0 : (int)(b0.w * f1.x + b1.x * f1.y + b1.y * f1.z);
        rA.z = pA.z < 0 ? 0 : (int)(b1.z * f2.x + b1.w * f2.y + b2.x * f2.z);
        rA.w = pA.w < 0 ? 0 : (int)(b2.y * f3.x + b2.z * f3.y + b2.w * f3.z);
        rB.x = pB.x < 0 ? 0 : (int)(b3.x * f4.x + b3.y * f4.y + b3.z * f4.z);
        rB.y = pB.y < 0 ? 0 : (int)(b3.w * f5.x + b4v.x * f5.y + b4v.y * f5.z);
        rB.z = pB.z < 0 ? 0 : (int)(b4v.z * f6.x + b4v.w * f6.y + b5.x * f6.z);
        rB.w = pB.w < 0 ? 0 : (int)(b5.y * f7.x + b5.z * f7.y + b5.w * f7.z);

        v4i* o4 = (v4i*)(out + base * 2);
        __builtin_nontemporal_store(rA, &o4[0]);
        __builtin_nontemporal_store(rB, &o4[1]);
    } else if (base < nPix) {
        // scalar tail
        for (long px = base; px < nPix; ++px) {
            int p0 = p2f[px * 2 + 0];
            int p1 = p2f[px * 2 + 1];
            const float* b = bary + px * 6;
            int r0 = 0, r1 = 0;
            if (p0 >= 0) {
                v4f f = fc[p0];
                r0 = (int)(b[0] * f.x + b[1] * f.y + b[2] * f.z);
            }
            if (p1 >= 0) {
                v4f f = fc[p1];
                r1 = (int)(b[3] * f.x + b[4] * f.y + b[5] * f.z);
            }
            out[px * 2 + 0] = r0;
            out[px * 2 + 1] = r1;
        }
    }
}

extern "C" void kernel_launch(void* const* d_in, const int* in_sizes, int n_in,
                              void* d_out, int out_size, void* d_ws, size_t ws_size,
                              hipStream_t stream) {
    const float* verts = (const float*)d_in[0];   // [N*V*D] f32, D=1
    const int*   faces = (const int*)d_in[1];     // [F,3] i32
    const int*   p2f   = (const int*)d_in[2];     // [N,H,W,K] i32
    const float* bary  = (const float*)d_in[3];   // [N,H,W,K,3] f32

    int  F    = in_sizes[1] / 3;
    long nPix = (long)in_sizes[2] / 2;            // K = 2
    int* out  = (int*)d_out;

    const int BLK = 256;

    face_attr_kernel<<<(F + BLK - 1) / BLK, BLK, 0, stream>>>(
        verts, faces, (v4f*)d_ws, F);

    long nThreads = (nPix + 3) / 4;
    int  grid     = (int)((nThreads + BLK - 1) / BLK);
    seg_kernel<<<grid, BLK, 0, stream>>>(
        p2f, bary, (const v4f*)d_ws, out, nPix);
}